// Round 7
// baseline (367.438 us; speedup 1.0000x reference)
//
#include <hip/hip_runtime.h>
#include <math.h>

#define N_NODES 50000
#define N_EDGES 400000
#define NB_SCAN 196   // ceil(50000/256)

typedef __attribute__((ext_vector_type(8))) short bf16x8;
typedef __attribute__((ext_vector_type(4))) float f32x4;

__device__ __forceinline__ float lrelu(float x){ return x > 0.f ? x : 0.2f*x; }
__device__ __forceinline__ unsigned short f2bf(float f){
    unsigned int b = __float_as_uint(f);
    return (unsigned short)((b + 0x7FFFu + ((b>>16)&1u)) >> 16);   // RNE
}
__device__ __forceinline__ void bf8_unpack(uint4 u, float f[8]){
    f[0] = __uint_as_float(u.x << 16);
    f[1] = __uint_as_float(u.x & 0xFFFF0000u);
    f[2] = __uint_as_float(u.y << 16);
    f[3] = __uint_as_float(u.y & 0xFFFF0000u);
    f[4] = __uint_as_float(u.z << 16);
    f[5] = __uint_as_float(u.z & 0xFFFF0000u);
    f[6] = __uint_as_float(u.w << 16);
    f[7] = __uint_as_float(u.w & 0xFFFF0000u);
}

// ---------------- CSR build ----------------
__global__ void hist_k(const int* __restrict__ dst, int* __restrict__ counts){
    int e = blockIdx.x*256 + threadIdx.x;
    if (e < N_EDGES) atomicAdd(&counts[dst[e]], 1);
}

__global__ void breduce_k(const int* __restrict__ counts, int* __restrict__ bsum){
    __shared__ int s[256];
    int i = blockIdx.x*256 + threadIdx.x;
    int v = (i < N_NODES) ? counts[i] : 0;
    s[threadIdx.x] = v; __syncthreads();
    for (int d = 128; d > 0; d >>= 1){
        if (threadIdx.x < d) s[threadIdx.x] += s[threadIdx.x + d];
        __syncthreads();
    }
    if (threadIdx.x == 0) bsum[blockIdx.x] = s[0];
}

__global__ void bscan_k(const int* __restrict__ bsum, int* __restrict__ bscan){
    __shared__ int s[256];
    int t = threadIdx.x;
    int v = (t < NB_SCAN) ? bsum[t] : 0;
    s[t] = v; __syncthreads();
    for (int d = 1; d < 256; d <<= 1){
        int x = (t >= d) ? s[t-d] : 0;
        __syncthreads();
        s[t] += x;
        __syncthreads();
    }
    if (t < NB_SCAN) bscan[t] = s[t] - v;   // exclusive
}

__global__ void scanfinal_k(const int* __restrict__ counts, const int* __restrict__ bscan,
                            int* __restrict__ offsets, int* __restrict__ cursor){
    __shared__ int s[256];
    int t = threadIdx.x; int i = blockIdx.x*256 + t;
    int v = (i < N_NODES) ? counts[i] : 0;
    s[t] = v; __syncthreads();
    for (int d = 1; d < 256; d <<= 1){
        int x = (t >= d) ? s[t-d] : 0;
        __syncthreads();
        s[t] += x;
        __syncthreads();
    }
    if (i < N_NODES){
        int off = s[t] - v + bscan[blockIdx.x];
        offsets[i] = off; cursor[i] = off;
    }
}

__global__ void scatter_k(const int* __restrict__ src, const int* __restrict__ dst,
                          int* __restrict__ cursor,
                          int* __restrict__ csr_src, int* __restrict__ csr_dst){
    int e = blockIdx.x*256 + threadIdx.x;
    if (e < N_EDGES){
        int d = dst[e];
        int pos = atomicAdd(&cursor[d], 1);
        csr_src[pos] = src[e];
        csr_dst[pos] = d;
    }
}

// ---------------- weight prep: W casts + folded attention vectors ----------------
// blocks 0..127: W1T[n][k]=W1[k][n] (256x128), WmlT[n][k]={W_mu|W_ls}[k][n] (128x256)
// blocks 128..129: v1[k] float4 = (s_h0,s_h1,d_h0,d_h1)[k], v_h = W1_h @ att_h  (k<128)
// blocks 130..133: v2[k] float4 = (s_mu,s_ls,d_mu,d_ls)[k], over 64-dim att  (k<256)
__global__ void prep_k(const float* __restrict__ W1,
                       const float* __restrict__ Wmu, const float* __restrict__ Wls,
                       const float* __restrict__ as1v, const float* __restrict__ ad1v,
                       const float* __restrict__ asmu, const float* __restrict__ asls,
                       const float* __restrict__ admu, const float* __restrict__ adls,
                       unsigned short* __restrict__ W1T, unsigned short* __restrict__ WmlT,
                       float* __restrict__ v1f, float* __restrict__ v2f){
    int b = blockIdx.x, t = threadIdx.x;
    if (b < 128){
        int i = b*256 + t;
        int n = i >> 7, k = i & 127;
        W1T[i] = f2bf(W1[k*256 + n]);
        int n2 = i >> 8, k2 = i & 255;
        float v = (n2 < 64) ? Wmu[k2*64 + n2] : Wls[k2*64 + (n2-64)];
        WmlT[i] = f2bf(v);
    } else if (b < 130){
        int idx = (b-128)*256 + t;          // 0..511
        int k = idx & 127, sel = idx >> 7;  // sel: 0=s_h0 1=s_h1 2=d_h0 3=d_h1
        int h = sel & 1;
        const float* att = (sel < 2) ? as1v : ad1v;
        float acc = 0.f;
        for (int c = 0; c < 128; c++)
            acc = fmaf(W1[k*256 + h*128 + c], att[h*128 + c], acc);
        v1f[k*4 + sel] = acc;
    } else {
        int idx = (b-130)*256 + t;          // 0..1023
        int k = idx & 255, sel = idx >> 8;  // sel: 0=s_mu 1=s_ls 2=d_mu 3=d_ls
        int g = sel & 1;
        const float* W = g ? Wls : Wmu;
        const float* att = (sel < 2) ? (g ? asls : asmu) : (g ? adls : admu);
        float acc = 0.f;
        for (int c = 0; c < 64; c++)
            acc = fmaf(W[k*64 + c], att[c], acc);
        v2f[k*4 + sel] = acc;
    }
}

// ---------------- x -> bf16 cast + conv1 attention logits (fp32) ----------------
__global__ __launch_bounds__(256) void castx_att_k(const float* __restrict__ x,
        const float4* __restrict__ v1,
        unsigned short* __restrict__ xb,
        float2* __restrict__ as1, float2* __restrict__ ad1){
    int wave = threadIdx.x >> 6, lane = threadIdx.x & 63;
    int n = blockIdx.x*4 + wave;
    float2 xv = ((const float2*)(x + (size_t)n*128))[lane];
    float4 va = v1[lane*2], vb = v1[lane*2 + 1];
    float s0 = xv.x*va.x + xv.y*vb.x;
    float s1 = xv.x*va.y + xv.y*vb.y;
    float d0 = xv.x*va.z + xv.y*vb.z;
    float d1 = xv.x*va.w + xv.y*vb.w;
    ((unsigned*)xb)[(size_t)n*64 + lane] = f2bf(xv.x) | ((unsigned)f2bf(xv.y) << 16);
    for (int o = 32; o; o >>= 1){
        s0 += __shfl_xor(s0, o); s1 += __shfl_xor(s1, o);
        d0 += __shfl_xor(d0, o); d1 += __shfl_xor(d1, o);
    }
    if (lane == 0){ as1[n] = make_float2(s0, s1); ad1[n] = make_float2(d0, d1); }
}

// ---------------- per-edge softmax weights + denominators (edge-parallel) ----------------
__global__ void weight_k(const int* __restrict__ csr_src, const int* __restrict__ csr_dst,
        const float2* __restrict__ as, const float2* __restrict__ ad,
        float2* __restrict__ w, float* __restrict__ den){
    int p = blockIdx.x*256 + threadIdx.x;
    if (p >= N_EDGES) return;
    int s = csr_src[p], d = csr_dst[p];
    float2 a = as[s], b = ad[d];
    float w0 = __expf(lrelu(a.x + b.x));
    float w1 = __expf(lrelu(a.y + b.y));
    w[p] = make_float2(w0, w1);
    atomicAdd(&den[2*(size_t)d],     w0);
    atomicAdd(&den[2*(size_t)d + 1], w1);
}

// ---------------- conv1 input-space aggregation: xagg[n] = norm(Sum w_h * x[src]) ----------------
// 1 wave/node; 4 edge-slots x 16 lanes; lane owns 8 ch (uint4) of the 128-ch x row.
// xagg row [0:128)=head0, [128:256)=head1 (bf16). grid 12500.
__global__ __launch_bounds__(256) void aggx_k(const unsigned short* __restrict__ xb,
        const float2* __restrict__ as1, const float2* __restrict__ ad1,
        const float* __restrict__ den1,
        const int* __restrict__ counts, const int* __restrict__ offsets,
        const int* __restrict__ csr_src, const float2* __restrict__ w1,
        unsigned short* __restrict__ xagg){
    int wave = threadIdx.x >> 6, lane = threadIdx.x & 63;
    int slot = lane >> 4, l16 = lane & 15;
    int n = blockIdx.x*4 + wave;
    const uint4* xv = (const uint4*)xb;   // 16 uint4 per row

    float2 asn = as1[n], adn = ad1[n];
    float ws0 = __expf(lrelu(asn.x + adn.x));
    float ws1 = __expf(lrelu(asn.y + adn.y));
    float invd0 = 1.f / (den1[2*(size_t)n]     + ws0 + 1e-16f);
    float invd1 = 1.f / (den1[2*(size_t)n + 1] + ws1 + 1e-16f);

    float a0[8] = {0,0,0,0,0,0,0,0}, a1[8] = {0,0,0,0,0,0,0,0};
    if (slot == 0){
        float rf[8]; bf8_unpack(xv[(size_t)n*16 + l16], rf);
        #pragma unroll
        for (int c = 0; c < 8; c++){ a0[c] = ws0*rf[c]; a1[c] = ws1*rf[c]; }
    }

    int off = offsets[n], deg = counts[n];
    for (int k = 0; k < deg; k += 4){
        int i = k + slot;
        bool v = i < deg;
        int idx = min(off + i, N_EDGES - 1);
        int s = csr_src[idx];
        float2 wv = w1[idx];
        if (!v){ wv.x = 0.f; wv.y = 0.f; }
        float rf[8]; bf8_unpack(xv[(size_t)s*16 + l16], rf);
        #pragma unroll
        for (int c = 0; c < 8; c++){
            a0[c] = fmaf(wv.x, rf[c], a0[c]);
            a1[c] = fmaf(wv.y, rf[c], a1[c]);
        }
    }

    #pragma unroll
    for (int c = 0; c < 8; c++){
        a0[c] += __shfl_xor(a0[c], 16); a0[c] += __shfl_xor(a0[c], 32);
        a1[c] += __shfl_xor(a1[c], 16); a1[c] += __shfl_xor(a1[c], 32);
    }

    if (slot < 2){
        float* acc = slot ? a1 : a0;
        float invd = slot ? invd1 : invd0;
        unsigned short ob[8];
        #pragma unroll
        for (int c = 0; c < 8; c++) ob[c] = f2bf(acc[c]*invd);
        uint4 o;
        o.x = ob[0] | ((unsigned)ob[1]<<16);
        o.y = ob[2] | ((unsigned)ob[3]<<16);
        o.z = ob[4] | ((unsigned)ob[5]<<16);
        o.w = ob[6] | ((unsigned)ob[7]<<16);
        ((uint4*)xagg)[(size_t)n*32 + slot*16 + l16] = o;
    }
}

// ---------------- bf16 MFMA GEMM ----------------
// MODE 0: plain bf16 C store (gemm2). MODE 1: +bias, ELU, bf16 store, fused as2/ad2 dots (gemm1b).
// A index: row*lda + blockIdx.x*acbs + k. BT index: (col0+r)*ldb + k.
template<int MODE>
__global__ __launch_bounds__(256) void mfma_gemm_k(const unsigned short* __restrict__ A,
        int lda, int acbs,
        const unsigned short* __restrict__ BT, int ldb,
        unsigned short* __restrict__ C, int ldc, int M, int K,
        const float* __restrict__ bias, const float4* __restrict__ v2,
        float* __restrict__ as2, float* __restrict__ ad2){
    __shared__ unsigned short As[128*40];   // +8 pad
    __shared__ unsigned short Bs[128*40];
    int t = threadIdx.x;
    int lane = t & 63, wid = t >> 6;
    int wy = wid >> 1, wx = wid & 1;
    int quad = lane >> 4, l15 = lane & 15;
    int row0 = blockIdx.y * 128;
    int col0 = blockIdx.x * 128;

    f32x4 acc[4][4];
    #pragma unroll
    for (int i = 0; i < 4; i++)
        #pragma unroll
        for (int j = 0; j < 4; j++)
            acc[i][j] = (f32x4){0.f, 0.f, 0.f, 0.f};

    int r = t >> 2;
    int cofs = (t & 3) * 8;
    int acol = blockIdx.x * acbs;

    for (int k0 = 0; k0 < K; k0 += 32){
        int gr0 = min(row0 + r,      M-1);
        int gr1 = min(row0 + r + 64, M-1);
        uint4 av0 = *(const uint4*)(A + (size_t)gr0*lda + acol + k0 + cofs);
        uint4 av1 = *(const uint4*)(A + (size_t)gr1*lda + acol + k0 + cofs);
        uint4 bv0 = *(const uint4*)(BT + (size_t)(col0 + r)*ldb      + k0 + cofs);
        uint4 bv1 = *(const uint4*)(BT + (size_t)(col0 + r + 64)*ldb + k0 + cofs);
        __syncthreads();
        *(uint4*)&As[r*40 + cofs]      = av0;
        *(uint4*)&As[(r+64)*40 + cofs] = av1;
        *(uint4*)&Bs[r*40 + cofs]      = bv0;
        *(uint4*)&Bs[(r+64)*40 + cofs] = bv1;
        __syncthreads();

        bf16x8 af[4], bf[4];
        #pragma unroll
        for (int i = 0; i < 4; i++)
            af[i] = *(const bf16x8*)&As[(wy*64 + i*16 + l15)*40 + quad*8];
        #pragma unroll
        for (int j = 0; j < 4; j++)
            bf[j] = *(const bf16x8*)&Bs[(wx*64 + j*16 + l15)*40 + quad*8];
        #pragma unroll
        for (int i = 0; i < 4; i++)
            #pragma unroll
            for (int j = 0; j < 4; j++)
                acc[i][j] = __builtin_amdgcn_mfma_f32_16x16x32_bf16(af[i], bf[j], acc[i][j], 0, 0, 0);
    }

    if (MODE == 0){
        #pragma unroll
        for (int i = 0; i < 4; i++){
            #pragma unroll
            for (int reg = 0; reg < 4; reg++){
                int rr = row0 + wy*64 + i*16 + quad*4 + reg;
                if (rr < M){
                    #pragma unroll
                    for (int j = 0; j < 4; j++){
                        int cc = col0 + wx*64 + j*16 + l15;
                        C[(size_t)rr*ldc + cc] = f2bf(acc[i][j][reg]);
                    }
                }
            }
        }
    } else {
        float bj[4]; float4 vj[4];
        #pragma unroll
        for (int j = 0; j < 4; j++){
            int cc = col0 + wx*64 + j*16 + l15;
            bj[j] = bias[cc]; vj[j] = v2[cc];
        }
        #pragma unroll
        for (int i = 0; i < 4; i++){
            #pragma unroll
            for (int reg = 0; reg < 4; reg++){
                int rr = row0 + wy*64 + i*16 + quad*4 + reg;
                float psm = 0.f, psl = 0.f, pdm = 0.f, pdl = 0.f;
                #pragma unroll
                for (int j = 0; j < 4; j++){
                    float h = acc[i][j][reg] + bj[j];
                    h = h > 0.f ? h : __expf(h) - 1.f;     // ELU
                    if (rr < M){
                        int cc = col0 + wx*64 + j*16 + l15;
                        C[(size_t)rr*ldc + cc] = f2bf(h);
                    }
                    psm = fmaf(h, vj[j].x, psm); psl = fmaf(h, vj[j].y, psl);
                    pdm = fmaf(h, vj[j].z, pdm); pdl = fmaf(h, vj[j].w, pdl);
                }
                #pragma unroll
                for (int o = 8; o; o >>= 1){
                    psm += __shfl_down(psm, o, 16); psl += __shfl_down(psl, o, 16);
                    pdm += __shfl_down(pdm, o, 16); pdl += __shfl_down(pdl, o, 16);
                }
                if (l15 == 0 && rr < M){
                    atomicAdd(as2 + 2*(size_t)rr,     psm);
                    atomicAdd(as2 + 2*(size_t)rr + 1, psl);
                    atomicAdd(ad2 + 2*(size_t)rr,     pdm);
                    atomicAdd(ad2 + 2*(size_t)rr + 1, pdl);
                }
            }
        }
    }
}

// ---------------- conv_mu/ls output-space aggregation (precomputed weights) ----------------
// 1 wave/node; 4 edge-slots x 16 lanes; l16 owns 8ch of hml's 128; g=l16>>3 (0=mu,1=ls).
__global__ __launch_bounds__(256) void agg2_k(const unsigned short* __restrict__ hml,
        const float2* __restrict__ as, const float2* __restrict__ ad,
        const float* __restrict__ den,
        const int* __restrict__ counts, const int* __restrict__ offsets,
        const int* __restrict__ csr_src, const float2* __restrict__ w2,
        const float* __restrict__ b_mu, const float* __restrict__ b_ls,
        float* __restrict__ out){
    int wave = threadIdx.x >> 6, lane = threadIdx.x & 63;
    int slot = lane >> 4, l16 = lane & 15;
    int n = blockIdx.x*4 + wave;
    int g = l16 >> 3;
    const uint4* hv = (const uint4*)hml;   // 16 uint4 per row

    float2 asn = as[n], adn = ad[n];
    float wself = __expf(lrelu((g ? asn.y : asn.x) + (g ? adn.y : adn.x)));
    float invd = 1.f / (den[2*(size_t)n + g] + wself + 1e-16f);

    float acc[8] = {0,0,0,0,0,0,0,0};
    if (slot == 0){
        float rf[8]; bf8_unpack(hv[(size_t)n*16 + l16], rf);
        #pragma unroll
        for (int c = 0; c < 8; c++) acc[c] = wself * rf[c];
    }

    int off = offsets[n], deg = counts[n];
    for (int k = 0; k < deg; k += 4){
        int i = k + slot;
        bool v = i < deg;
        int idx = min(off + i, N_EDGES - 1);
        int s = csr_src[idx];
        float2 wv = w2[idx];
        float w = g ? wv.y : wv.x;
        if (!v) w = 0.f;
        float rf[8]; bf8_unpack(hv[(size_t)s*16 + l16], rf);
        #pragma unroll
        for (int c = 0; c < 8; c++) acc[c] = fmaf(w, rf[c], acc[c]);
    }

    #pragma unroll
    for (int c = 0; c < 8; c++){
        acc[c] += __shfl_xor(acc[c], 16);
        acc[c] += __shfl_xor(acc[c], 32);
    }

    if (slot == 0){
        int c0 = (l16 & 7) * 8;
        const float* bb = g ? b_ls : b_mu;
        float* base = g ? (out + (size_t)N_NODES*64) : out;
        float ov[8];
        #pragma unroll
        for (int c = 0; c < 8; c++) ov[c] = acc[c]*invd + bb[c0+c];
        *(float4*)&base[(size_t)n*64 + c0]     = *(float4*)&ov[0];
        *(float4*)&base[(size_t)n*64 + c0 + 4] = *(float4*)&ov[4];
    }
}

extern "C" void kernel_launch(void* const* d_in, const int* in_sizes, int n_in,
                              void* d_out, int out_size, void* d_ws, size_t ws_size,
                              hipStream_t stream) {
    const float* x           = (const float*)d_in[0];
    const int*   ei          = (const int*)d_in[1];
    const float* W1          = (const float*)d_in[2];
    const float* att_src1    = (const float*)d_in[3];
    const float* att_dst1    = (const float*)d_in[4];
    const float* b1          = (const float*)d_in[5];
    const float* W_mu        = (const float*)d_in[6];
    const float* att_src_mu  = (const float*)d_in[7];
    const float* att_dst_mu  = (const float*)d_in[8];
    const float* b_mu        = (const float*)d_in[9];
    const float* W_ls        = (const float*)d_in[10];
    const float* att_src_ls  = (const float*)d_in[11];
    const float* att_dst_ls  = (const float*)d_in[12];
    const float* b_ls        = (const float*)d_in[13];
    float* out = (float*)d_out;

    const int* srcp = ei;
    const int* dstp = ei + N_EDGES;

    // workspace ~51 MB (safe envelope proven >= 67.9 MB, r4).
    // hml aliases xb (xb dead after aggx; gemm2 writes hml afterwards).
    // xagg [N,256]bf16 = 25.6MB aliases d_out (re-poisoned each call; dead before agg2 writes out).
    unsigned short* xb    = (unsigned short*)d_ws;           // [N,128] bf16
    unsigned short* hml   = xb;                              // [N,128] bf16 (alias)
    unsigned short* hbuf  = xb   + (size_t)N_NODES*128;      // [N,256] bf16
    unsigned short* W1T   = hbuf + (size_t)N_NODES*256;      // [256,128]
    unsigned short* WmlT  = W1T  + 32768;                    // [128,256]
    float4* v1   = (float4*)(WmlT + 32768);                  // [128]
    float4* v2   = v1 + 128;                                 // [256]
    float2* as1  = (float2*)(v2 + 256);                      // [N]
    float2* ad1  = as1 + N_NODES;
    float2* as2  = ad1 + N_NODES;                            // ---- zeroed start
    float2* ad2  = as2 + N_NODES;
    float*  den1 = (float*)(ad2 + N_NODES);                  // [N*2]
    float*  den2 = den1 + 2*(size_t)N_NODES;                 // [N*2]
    int*    counts = (int*)(den2 + 2*(size_t)N_NODES);       // ---- zeroed end
    int*    offsets= counts + N_NODES;
    int*    cursor = offsets + N_NODES;
    int*    bsum   = cursor + N_NODES;                       // [256]
    int*    bscan  = bsum + 256;                             // [256]
    int*    csr_src= bscan + 256;                            // [E]
    int*    csr_dst= csr_src + N_EDGES;                      // [E]
    float2* w1     = (float2*)(csr_dst + N_EDGES);           // [E]
    float2* w2     = w1 + N_EDGES;                           // [E]
    unsigned short* xagg = (unsigned short*)d_out;           // [N,256] bf16 (alias d_out)

    const int EB = (N_EDGES + 255) / 256;

    // zero atomic targets: as2, ad2, den1, den2, counts (contiguous)
    hipMemsetAsync(as2, 0, 2*(size_t)N_NODES*sizeof(float2)
                           + 4*(size_t)N_NODES*sizeof(float)
                           + N_NODES*sizeof(int), stream);

    // --- CSR build (src + dst per position) ---
    hist_k<<<EB, 256, 0, stream>>>(dstp, counts);
    breduce_k<<<NB_SCAN, 256, 0, stream>>>(counts, bsum);
    bscan_k<<<1, 256, 0, stream>>>(bsum, bscan);
    scanfinal_k<<<NB_SCAN, 256, 0, stream>>>(counts, bscan, offsets, cursor);
    scatter_k<<<EB, 256, 0, stream>>>(srcp, dstp, cursor, csr_src, csr_dst);

    // --- weight prep (casts + folded attention vectors) ---
    prep_k<<<134, 256, 0, stream>>>(W1, W_mu, W_ls,
                                    att_src1, att_dst1,
                                    att_src_mu, att_src_ls, att_dst_mu, att_dst_ls,
                                    W1T, WmlT, (float*)v1, (float*)v2);

    // --- conv1: logits from x directly; aggregate x; then GEMM ---
    castx_att_k<<<N_NODES/4, 256, 0, stream>>>(x, v1, xb, as1, ad1);
    weight_k<<<EB, 256, 0, stream>>>(csr_src, csr_dst, as1, ad1, w1, den1);
    aggx_k<<<N_NODES/4, 256, 0, stream>>>(xb, as1, ad1, den1, counts, offsets, csr_src, w1, xagg);
    // hbuf = ELU(xagg_h @ W1_h + b1); fused as2/ad2 logit dots
    mfma_gemm_k<1><<<dim3(2, 391), 256, 0, stream>>>(xagg, 256, 128, W1T, 128,
            hbuf, 256, N_NODES, 128, b1, v2, (float*)as2, (float*)ad2);

    // --- conv_mu + conv_ls: transform then aggregate (out-space 128ch < in-space 256ch) ---
    mfma_gemm_k<0><<<dim3(1, 391), 256, 0, stream>>>(hbuf, 256, 0, WmlT, 256,
            hml, 128, N_NODES, 256, nullptr, nullptr, nullptr, nullptr);
    weight_k<<<EB, 256, 0, stream>>>(csr_src, csr_dst, as2, ad2, w2, den2);
    agg2_k<<<N_NODES/4, 256, 0, stream>>>(hml, as2, ad2, den2, counts, offsets, csr_src,
                                          w2, b_mu, b_ls, out);
}

// Round 8
// 282.841 us; speedup vs baseline: 1.2991x; 1.2991x over previous
//
#include <hip/hip_runtime.h>
#include <math.h>

#define N_NODES 50000
#define N_EDGES 400000
#define NB_SCAN 196   // ceil(50000/256)

typedef __attribute__((ext_vector_type(8))) short bf16x8;
typedef __attribute__((ext_vector_type(4))) float f32x4;

__device__ __forceinline__ float lrelu(float x){ return x > 0.f ? x : 0.2f*x; }
__device__ __forceinline__ unsigned short f2bf(float f){
    unsigned int b = __float_as_uint(f);
    return (unsigned short)((b + 0x7FFFu + ((b>>16)&1u)) >> 16);   // RNE
}
__device__ __forceinline__ void bf8_unpack(uint4 u, float f[8]){
    f[0] = __uint_as_float(u.x << 16);
    f[1] = __uint_as_float(u.x & 0xFFFF0000u);
    f[2] = __uint_as_float(u.y << 16);
    f[3] = __uint_as_float(u.y & 0xFFFF0000u);
    f[4] = __uint_as_float(u.z << 16);
    f[5] = __uint_as_float(u.z & 0xFFFF0000u);
    f[6] = __uint_as_float(u.w << 16);
    f[7] = __uint_as_float(u.w & 0xFFFF0000u);
}

// ---------------- CSR build ----------------
__global__ void hist_k(const int* __restrict__ dst, int* __restrict__ counts){
    int e = blockIdx.x*256 + threadIdx.x;
    if (e < N_EDGES) atomicAdd(&counts[dst[e]], 1);
}

__global__ void breduce_k(const int* __restrict__ counts, int* __restrict__ bsum){
    __shared__ int s[256];
    int i = blockIdx.x*256 + threadIdx.x;
    int v = (i < N_NODES) ? counts[i] : 0;
    s[threadIdx.x] = v; __syncthreads();
    for (int d = 128; d > 0; d >>= 1){
        if (threadIdx.x < d) s[threadIdx.x] += s[threadIdx.x + d];
        __syncthreads();
    }
    if (threadIdx.x == 0) bsum[blockIdx.x] = s[0];
}

__global__ void bscan_k(const int* __restrict__ bsum, int* __restrict__ bscan){
    __shared__ int s[256];
    int t = threadIdx.x;
    int v = (t < NB_SCAN) ? bsum[t] : 0;
    s[t] = v; __syncthreads();
    for (int d = 1; d < 256; d <<= 1){
        int x = (t >= d) ? s[t-d] : 0;
        __syncthreads();
        s[t] += x;
        __syncthreads();
    }
    if (t < NB_SCAN) bscan[t] = s[t] - v;   // exclusive
}

__global__ void scanfinal_k(const int* __restrict__ counts, const int* __restrict__ bscan,
                            int* __restrict__ offsets, int* __restrict__ cursor){
    __shared__ int s[256];
    int t = threadIdx.x; int i = blockIdx.x*256 + t;
    int v = (i < N_NODES) ? counts[i] : 0;
    s[t] = v; __syncthreads();
    for (int d = 1; d < 256; d <<= 1){
        int x = (t >= d) ? s[t-d] : 0;
        __syncthreads();
        s[t] += x;
        __syncthreads();
    }
    if (i < N_NODES){
        int off = s[t] - v + bscan[blockIdx.x];
        offsets[i] = off; cursor[i] = off;
    }
}

__global__ void scatter_k(const int* __restrict__ src, const int* __restrict__ dst,
                          int* __restrict__ cursor, int* __restrict__ csr_src){
    int e = blockIdx.x*256 + threadIdx.x;
    if (e < N_EDGES){
        int d = dst[e];
        int pos = atomicAdd(&cursor[d], 1);
        csr_src[pos] = src[e];
    }
}

// ---------------- weight prep: W casts + folded attention vectors ----------------
__global__ void prep_k(const float* __restrict__ W1,
                       const float* __restrict__ Wmu, const float* __restrict__ Wls,
                       const float* __restrict__ as1v, const float* __restrict__ ad1v,
                       const float* __restrict__ asmu, const float* __restrict__ asls,
                       const float* __restrict__ admu, const float* __restrict__ adls,
                       unsigned short* __restrict__ W1T, unsigned short* __restrict__ WmlT,
                       float* __restrict__ v1f, float* __restrict__ v2f){
    int b = blockIdx.x, t = threadIdx.x;
    if (b < 128){
        int i = b*256 + t;
        int n = i >> 7, k = i & 127;
        W1T[i] = f2bf(W1[k*256 + n]);
        int n2 = i >> 8, k2 = i & 255;
        float v = (n2 < 64) ? Wmu[k2*64 + n2] : Wls[k2*64 + (n2-64)];
        WmlT[i] = f2bf(v);
    } else if (b < 130){
        int idx = (b-128)*256 + t;          // 0..511
        int k = idx & 127, sel = idx >> 7;  // 0=s_h0 1=s_h1 2=d_h0 3=d_h1
        int h = sel & 1;
        const float* att = (sel < 2) ? as1v : ad1v;
        float acc = 0.f;
        for (int c = 0; c < 128; c++)
            acc = fmaf(W1[k*256 + h*128 + c], att[h*128 + c], acc);
        v1f[k*4 + sel] = acc;
    } else {
        int idx = (b-130)*256 + t;          // 0..1023
        int k = idx & 255, sel = idx >> 8;  // 0=s_mu 1=s_ls 2=d_mu 3=d_ls
        int g = sel & 1;
        const float* W = g ? Wls : Wmu;
        const float* att = (sel < 2) ? (g ? asls : asmu) : (g ? adls : admu);
        float acc = 0.f;
        for (int c = 0; c < 64; c++)
            acc = fmaf(W[k*64 + c], att[c], acc);
        v2f[k*4 + sel] = acc;
    }
}

// ---------------- x -> bf16 cast + conv1 attention logits (fp32) ----------------
__global__ __launch_bounds__(256) void castx_att_k(const float* __restrict__ x,
        const float4* __restrict__ v1,
        unsigned short* __restrict__ xb,
        float2* __restrict__ as1, float2* __restrict__ ad1){
    int wave = threadIdx.x >> 6, lane = threadIdx.x & 63;
    int n = blockIdx.x*4 + wave;
    float2 xv = ((const float2*)(x + (size_t)n*128))[lane];
    float4 va = v1[lane*2], vb = v1[lane*2 + 1];
    float s0 = xv.x*va.x + xv.y*vb.x;
    float s1 = xv.x*va.y + xv.y*vb.y;
    float d0 = xv.x*va.z + xv.y*vb.z;
    float d1 = xv.x*va.w + xv.y*vb.w;
    ((unsigned*)xb)[(size_t)n*64 + lane] = f2bf(xv.x) | ((unsigned)f2bf(xv.y) << 16);
    for (int o = 32; o; o >>= 1){
        s0 += __shfl_xor(s0, o); s1 += __shfl_xor(s1, o);
        d0 += __shfl_xor(d0, o); d1 += __shfl_xor(d1, o);
    }
    if (lane == 0){ as1[n] = make_float2(s0, s1); ad1[n] = make_float2(d0, d1); }
}

// ---------------- conv1 input-space aggregation, inline weights + inline denominator ----------------
// 1 wave/node; 4 edge-slots x 16 lanes; lane owns 8 ch (uint4) of the 128-ch x row.
// xagg row [0:128)=head0, [128:256)=head1 (bf16). grid 12500.
__global__ __launch_bounds__(256) void aggx_k(const unsigned short* __restrict__ xb,
        const float2* __restrict__ as1, const float2* __restrict__ ad1,
        const int* __restrict__ counts, const int* __restrict__ offsets,
        const int* __restrict__ csr_src,
        unsigned short* __restrict__ xagg){
    int wave = threadIdx.x >> 6, lane = threadIdx.x & 63;
    int slot = lane >> 4, l16 = lane & 15;
    int n = blockIdx.x*4 + wave;
    const uint4* xv = (const uint4*)xb;   // 16 uint4 per row

    float2 asn = as1[n], adn = ad1[n];
    float ws0 = __expf(lrelu(asn.x + adn.x));
    float ws1 = __expf(lrelu(asn.y + adn.y));

    float a0[8] = {0,0,0,0,0,0,0,0}, a1[8] = {0,0,0,0,0,0,0,0};
    float dp0 = 0.f, dp1 = 0.f;                // per-slot denominator partials
    if (slot == 0){
        float rf[8]; bf8_unpack(xv[(size_t)n*16 + l16], rf);
        #pragma unroll
        for (int c = 0; c < 8; c++){ a0[c] = ws0*rf[c]; a1[c] = ws1*rf[c]; }
        dp0 = ws0; dp1 = ws1;
    }

    int off = offsets[n], deg = counts[n];
    for (int k = 0; k < deg; k += 4){
        int i = k + slot;
        bool v = i < deg;
        int idx = min(off + i, N_EDGES - 1);
        int s = csr_src[idx];
        float2 a = as1[s];
        float w0 = v ? __expf(lrelu(a.x + adn.x)) : 0.f;
        float w1 = v ? __expf(lrelu(a.y + adn.y)) : 0.f;
        float rf[8]; bf8_unpack(xv[(size_t)s*16 + l16], rf);
        dp0 += w0; dp1 += w1;
        #pragma unroll
        for (int c = 0; c < 8; c++){
            a0[c] = fmaf(w0, rf[c], a0[c]);
            a1[c] = fmaf(w1, rf[c], a1[c]);
        }
    }

    #pragma unroll
    for (int c = 0; c < 8; c++){
        a0[c] += __shfl_xor(a0[c], 16); a0[c] += __shfl_xor(a0[c], 32);
        a1[c] += __shfl_xor(a1[c], 16); a1[c] += __shfl_xor(a1[c], 32);
    }
    dp0 += __shfl_xor(dp0, 16); dp0 += __shfl_xor(dp0, 32);
    dp1 += __shfl_xor(dp1, 16); dp1 += __shfl_xor(dp1, 32);

    if (slot < 2){
        float* acc = slot ? a1 : a0;
        float invd = 1.f / ((slot ? dp1 : dp0) + 1e-16f);
        unsigned short ob[8];
        #pragma unroll
        for (int c = 0; c < 8; c++) ob[c] = f2bf(acc[c]*invd);
        uint4 o;
        o.x = ob[0] | ((unsigned)ob[1]<<16);
        o.y = ob[2] | ((unsigned)ob[3]<<16);
        o.z = ob[4] | ((unsigned)ob[5]<<16);
        o.w = ob[6] | ((unsigned)ob[7]<<16);
        ((uint4*)xagg)[(size_t)n*32 + slot*16 + l16] = o;
    }
}

// ---------------- bf16 MFMA GEMM ----------------
// MODE 0: plain bf16 C store. MODE 1: +bias, ELU, bf16 store, fused as2/ad2 logit dots.
template<int MODE>
__global__ __launch_bounds__(256) void mfma_gemm_k(const unsigned short* __restrict__ A,
        int lda, int acbs,
        const unsigned short* __restrict__ BT, int ldb,
        unsigned short* __restrict__ C, int ldc, int M, int K,
        const float* __restrict__ bias, const float4* __restrict__ v2,
        float* __restrict__ as2, float* __restrict__ ad2){
    __shared__ unsigned short As[128*40];   // +8 pad
    __shared__ unsigned short Bs[128*40];
    int t = threadIdx.x;
    int lane = t & 63, wid = t >> 6;
    int wy = wid >> 1, wx = wid & 1;
    int quad = lane >> 4, l15 = lane & 15;
    int row0 = blockIdx.y * 128;
    int col0 = blockIdx.x * 128;

    f32x4 acc[4][4];
    #pragma unroll
    for (int i = 0; i < 4; i++)
        #pragma unroll
        for (int j = 0; j < 4; j++)
            acc[i][j] = (f32x4){0.f, 0.f, 0.f, 0.f};

    int r = t >> 2;
    int cofs = (t & 3) * 8;
    int acol = blockIdx.x * acbs;

    for (int k0 = 0; k0 < K; k0 += 32){
        int gr0 = min(row0 + r,      M-1);
        int gr1 = min(row0 + r + 64, M-1);
        uint4 av0 = *(const uint4*)(A + (size_t)gr0*lda + acol + k0 + cofs);
        uint4 av1 = *(const uint4*)(A + (size_t)gr1*lda + acol + k0 + cofs);
        uint4 bv0 = *(const uint4*)(BT + (size_t)(col0 + r)*ldb      + k0 + cofs);
        uint4 bv1 = *(const uint4*)(BT + (size_t)(col0 + r + 64)*ldb + k0 + cofs);
        __syncthreads();
        *(uint4*)&As[r*40 + cofs]      = av0;
        *(uint4*)&As[(r+64)*40 + cofs] = av1;
        *(uint4*)&Bs[r*40 + cofs]      = bv0;
        *(uint4*)&Bs[(r+64)*40 + cofs] = bv1;
        __syncthreads();

        bf16x8 af[4], bf[4];
        #pragma unroll
        for (int i = 0; i < 4; i++)
            af[i] = *(const bf16x8*)&As[(wy*64 + i*16 + l15)*40 + quad*8];
        #pragma unroll
        for (int j = 0; j < 4; j++)
            bf[j] = *(const bf16x8*)&Bs[(wx*64 + j*16 + l15)*40 + quad*8];
        #pragma unroll
        for (int i = 0; i < 4; i++)
            #pragma unroll
            for (int j = 0; j < 4; j++)
                acc[i][j] = __builtin_amdgcn_mfma_f32_16x16x32_bf16(af[i], bf[j], acc[i][j], 0, 0, 0);
    }

    if (MODE == 0){
        #pragma unroll
        for (int i = 0; i < 4; i++){
            #pragma unroll
            for (int reg = 0; reg < 4; reg++){
                int rr = row0 + wy*64 + i*16 + quad*4 + reg;
                if (rr < M){
                    #pragma unroll
                    for (int j = 0; j < 4; j++){
                        int cc = col0 + wx*64 + j*16 + l15;
                        C[(size_t)rr*ldc + cc] = f2bf(acc[i][j][reg]);
                    }
                }
            }
        }
    } else {
        float bj[4]; float4 vj[4];
        #pragma unroll
        for (int j = 0; j < 4; j++){
            int cc = col0 + wx*64 + j*16 + l15;
            bj[j] = bias[cc]; vj[j] = v2[cc];
        }
        #pragma unroll
        for (int i = 0; i < 4; i++){
            #pragma unroll
            for (int reg = 0; reg < 4; reg++){
                int rr = row0 + wy*64 + i*16 + quad*4 + reg;
                float psm = 0.f, psl = 0.f, pdm = 0.f, pdl = 0.f;
                #pragma unroll
                for (int j = 0; j < 4; j++){
                    float h = acc[i][j][reg] + bj[j];
                    h = h > 0.f ? h : __expf(h) - 1.f;     // ELU
                    if (rr < M){
                        int cc = col0 + wx*64 + j*16 + l15;
                        C[(size_t)rr*ldc + cc] = f2bf(h);
                    }
                    psm = fmaf(h, vj[j].x, psm); psl = fmaf(h, vj[j].y, psl);
                    pdm = fmaf(h, vj[j].z, pdm); pdl = fmaf(h, vj[j].w, pdl);
                }
                #pragma unroll
                for (int o = 8; o; o >>= 1){
                    psm += __shfl_down(psm, o, 16); psl += __shfl_down(psl, o, 16);
                    pdm += __shfl_down(pdm, o, 16); pdl += __shfl_down(pdl, o, 16);
                }
                if (l15 == 0 && rr < M){
                    atomicAdd(as2 + 2*(size_t)rr,     psm);
                    atomicAdd(as2 + 2*(size_t)rr + 1, psl);
                    atomicAdd(ad2 + 2*(size_t)rr,     pdm);
                    atomicAdd(ad2 + 2*(size_t)rr + 1, pdl);
                }
            }
        }
    }
}

// ---------------- conv_mu/ls aggregation, inline weights + inline denominator ----------------
// 1 wave/node; 4 edge-slots x 16 lanes; l16 owns 8ch of hml's 128; g=l16>>3 (0=mu,1=ls).
__global__ __launch_bounds__(256) void agg2_k(const unsigned short* __restrict__ hml,
        const float2* __restrict__ as, const float2* __restrict__ ad,
        const int* __restrict__ counts, const int* __restrict__ offsets,
        const int* __restrict__ csr_src,
        const float* __restrict__ b_mu, const float* __restrict__ b_ls,
        float* __restrict__ out){
    int wave = threadIdx.x >> 6, lane = threadIdx.x & 63;
    int slot = lane >> 4, l16 = lane & 15;
    int n = blockIdx.x*4 + wave;
    int g = l16 >> 3;
    const uint4* hv = (const uint4*)hml;   // 16 uint4 per row

    float2 asn = as[n], adn = ad[n];
    float adh = g ? adn.y : adn.x;
    float wself = __expf(lrelu((g ? asn.y : asn.x) + adh));

    float acc[8] = {0,0,0,0,0,0,0,0};
    float dp = 0.f;
    if (slot == 0){
        float rf[8]; bf8_unpack(hv[(size_t)n*16 + l16], rf);
        #pragma unroll
        for (int c = 0; c < 8; c++) acc[c] = wself * rf[c];
        dp = wself;
    }

    int off = offsets[n], deg = counts[n];
    for (int k = 0; k < deg; k += 4){
        int i = k + slot;
        bool v = i < deg;
        int idx = min(off + i, N_EDGES - 1);
        int s = csr_src[idx];
        float2 a = as[s];
        float w = v ? __expf(lrelu((g ? a.y : a.x) + adh)) : 0.f;
        float rf[8]; bf8_unpack(hv[(size_t)s*16 + l16], rf);
        dp += w;
        #pragma unroll
        for (int c = 0; c < 8; c++) acc[c] = fmaf(w, rf[c], acc[c]);
    }

    #pragma unroll
    for (int c = 0; c < 8; c++){
        acc[c] += __shfl_xor(acc[c], 16);
        acc[c] += __shfl_xor(acc[c], 32);
    }
    dp += __shfl_xor(dp, 16);
    dp += __shfl_xor(dp, 32);

    if (slot == 0){
        float invd = 1.f / (dp + 1e-16f);
        int c0 = (l16 & 7) * 8;
        const float* bb = g ? b_ls : b_mu;
        float* base = g ? (out + (size_t)N_NODES*64) : out;
        float ov[8];
        #pragma unroll
        for (int c = 0; c < 8; c++) ov[c] = acc[c]*invd + bb[c0+c];
        *(float4*)&base[(size_t)n*64 + c0]     = *(float4*)&ov[0];
        *(float4*)&base[(size_t)n*64 + c0 + 4] = *(float4*)&ov[4];
    }
}

extern "C" void kernel_launch(void* const* d_in, const int* in_sizes, int n_in,
                              void* d_out, int out_size, void* d_ws, size_t ws_size,
                              hipStream_t stream) {
    const float* x           = (const float*)d_in[0];
    const int*   ei          = (const int*)d_in[1];
    const float* W1          = (const float*)d_in[2];
    const float* att_src1    = (const float*)d_in[3];
    const float* att_dst1    = (const float*)d_in[4];
    const float* b1          = (const float*)d_in[5];
    const float* W_mu        = (const float*)d_in[6];
    const float* att_src_mu  = (const float*)d_in[7];
    const float* att_dst_mu  = (const float*)d_in[8];
    const float* b_mu        = (const float*)d_in[9];
    const float* W_ls        = (const float*)d_in[10];
    const float* att_src_ls  = (const float*)d_in[11];
    const float* att_dst_ls  = (const float*)d_in[12];
    const float* b_ls        = (const float*)d_in[13];
    float* out = (float*)d_out;

    const int* srcp = ei;
    const int* dstp = ei + N_EDGES;

    // workspace ~42 MB (safe envelope proven >= 67.9 MB at r4; r5's 68.7 corrupted).
    // hml aliases xb (xb dead after aggx; gemm2 writes hml afterwards).
    // xagg [N,256]bf16 = 25.6 MB aliases d_out (dead before agg2 writes out).
    unsigned short* xb    = (unsigned short*)d_ws;           // [N,128] bf16
    unsigned short* hml   = xb;                              // [N,128] bf16 (alias)
    unsigned short* hbuf  = xb   + (size_t)N_NODES*128;      // [N,256] bf16
    unsigned short* W1T   = hbuf + (size_t)N_NODES*256;      // [256,128]
    unsigned short* WmlT  = W1T  + 32768;                    // [128,256]
    float4* v1   = (float4*)(WmlT + 32768);                  // [128]
    float4* v2   = v1 + 128;                                 // [256]
    float2* as1  = (float2*)(v2 + 256);                      // [N]
    float2* ad1  = as1 + N_NODES;
    float2* as2  = ad1 + N_NODES;                            // ---- zeroed start
    float2* ad2  = as2 + N_NODES;
    int*    counts = (int*)(ad2 + N_NODES);                  // ---- zeroed end
    int*    offsets= counts + N_NODES;
    int*    cursor = offsets + N_NODES;
    int*    bsum   = cursor + N_NODES;                       // [256]
    int*    bscan  = bsum + 256;                             // [256]
    int*    csr_src= bscan + 256;                            // [E]
    unsigned short* xagg = (unsigned short*)d_out;           // [N,256] bf16 (alias d_out)

    const int EB = (N_EDGES + 255) / 256;

    // zero atomic targets: as2, ad2 (gemm1 epilogue), counts (contiguous)
    hipMemsetAsync(as2, 0, 2*(size_t)N_NODES*sizeof(float2) + N_NODES*sizeof(int), stream);

    // --- CSR build ---
    hist_k<<<EB, 256, 0, stream>>>(dstp, counts);
    breduce_k<<<NB_SCAN, 256, 0, stream>>>(counts, bsum);
    bscan_k<<<1, 256, 0, stream>>>(bsum, bscan);
    scanfinal_k<<<NB_SCAN, 256, 0, stream>>>(counts, bscan, offsets, cursor);
    scatter_k<<<EB, 256, 0, stream>>>(srcp, dstp, cursor, csr_src);

    // --- weight prep (casts + folded attention vectors) ---
    prep_k<<<134, 256, 0, stream>>>(W1, W_mu, W_ls,
                                    att_src1, att_dst1,
                                    att_src_mu, att_src_ls, att_dst_mu, att_dst_ls,
                                    W1T, WmlT, (float*)v1, (float*)v2);

    // --- conv1: logits from x directly; aggregate x (inline softmax); then GEMM ---
    castx_att_k<<<N_NODES/4, 256, 0, stream>>>(x, v1, xb, as1, ad1);
    aggx_k<<<N_NODES/4, 256, 0, stream>>>(xb, as1, ad1, counts, offsets, csr_src, xagg);
    // hbuf = ELU(xagg_h @ W1_h + b1); fused as2/ad2 logit dots
    mfma_gemm_k<1><<<dim3(2, 391), 256, 0, stream>>>(xagg, 256, 128, W1T, 128,
            hbuf, 256, N_NODES, 128, b1, v2, (float*)as2, (float*)ad2);

    // --- conv_mu + conv_ls: transform then aggregate ---
    mfma_gemm_k<0><<<dim3(1, 391), 256, 0, stream>>>(hbuf, 256, 0, WmlT, 256,
            hml, 128, N_NODES, 256, nullptr, nullptr, nullptr, nullptr);
    agg2_k<<<N_NODES/4, 256, 0, stream>>>(hml, as2, ad2, counts, offsets, csr_src,
                                          b_mu, b_ls, out);
}